// Round 6
// baseline (677.126 us; speedup 1.0000x reference)
//
#include <hip/hip_runtime.h>
#include <math.h>

#define NDIM 256
#define VOL  (NDIM*NDIM*NDIM)      // 16777216 elements per batch-channel volume
#define NB   128                    // kept bins 0..127; label 128 is dropped

// base-4 digit reversal of an 8-bit index (involution)
__device__ __forceinline__ int dr4(int x) {
    int b = (int)(__brev((unsigned)x) >> 24);
    return ((b >> 1) & 0x55) | ((b << 1) & 0xAA);
}
__device__ __forceinline__ float2 cmul(float2 a, float2 b) {
    return make_float2(a.x * b.x - a.y * b.y, a.x * b.y + a.y * b.x);
}
__device__ __forceinline__ float2 cadd(float2 a, float2 b){ return make_float2(a.x+b.x, a.y+b.y); }
__device__ __forceinline__ float2 csub(float2 a, float2 b){ return make_float2(a.x-b.x, a.y-b.y); }
__device__ __forceinline__ float2 cmuli_neg(float2 a){ return make_float2(a.y, -a.x); }  // -i*a
__device__ __forceinline__ float2 cmuli_pos(float2 a){ return make_float2(-a.y, a.x); }  // +i*a

// ---------------------------------------------------------------------------
// Pass 1: pack (ref + i*pred), radix-4 Stockham FFT along z. One WAVE per
// 256-pt line (wave-private LDS, no barriers). Stage 0 reads global directly;
// stage 3 writes global directly. Natural-order output.
// ---------------------------------------------------------------------------
__global__ __launch_bounds__(256) void fftz_pack(const float* __restrict__ re_in,
                                                 const float* __restrict__ im_in,
                                                 float2* __restrict__ out)
{
    __shared__ float2 buf[4][2][NDIM];   // 16 KB, per-wave double buffer
    const int t = threadIdx.x;
    const int w = t >> 6, j = t & 63;
    const int L = blockIdx.x * 4 + w;    // line id in [0, 65536)
    const float* rp = re_in + (size_t)L * NDIM;
    const float* ip = im_in + (size_t)L * NDIM;

    float2 v0 = make_float2(rp[j      ], ip[j      ]);
    float2 v1 = make_float2(rp[j +  64], ip[j +  64]);
    float2 v2 = make_float2(rp[j + 128], ip[j + 128]);
    float2 v3 = make_float2(rp[j + 192], ip[j + 192]);

    // stage 0 (Ns=1, twiddle = 1): write at 4j + r
    {
        float2 t0=cadd(v0,v2), t1=csub(v0,v2), t2=cadd(v1,v3), t3=csub(v1,v3);
        buf[w][0][4*j    ] = cadd(t0, t2);
        buf[w][0][4*j + 1] = cadd(t1, cmuli_neg(t3));
        buf[w][0][4*j + 2] = csub(t0, t2);
        buf[w][0][4*j + 3] = cadd(t1, cmuli_pos(t3));
    }
    __builtin_amdgcn_sched_barrier(0);

    int p = 0;
    #pragma unroll
    for (int stage = 1; stage <= 2; ++stage) {
        const int Ns = (stage == 1) ? 4 : 16;
        const int jm = j & (Ns - 1);
        float2 a0 = buf[w][p][j      ];
        float2 a1 = buf[w][p][j +  64];
        float2 a2 = buf[w][p][j + 128];
        float2 a3 = buf[w][p][j + 192];
        float sn, cs;
        __sincosf(-(float)(2.0 * M_PI) * (float)jm / (float)(4 * Ns), &sn, &cs);
        float2 w1 = make_float2(cs, sn);
        float2 w2 = cmul(w1, w1);
        float2 w3 = cmul(w2, w1);
        a1 = cmul(a1, w1); a2 = cmul(a2, w2); a3 = cmul(a3, w3);
        float2 t0=cadd(a0,a2), t1=csub(a0,a2), t2=cadd(a1,a3), t3=csub(a1,a3);
        const int idxD = (j / Ns) * (4 * Ns) + jm;
        buf[w][p^1][idxD         ] = cadd(t0, t2);
        buf[w][p^1][idxD +     Ns] = cadd(t1, cmuli_neg(t3));
        buf[w][p^1][idxD + 2 * Ns] = csub(t0, t2);
        buf[w][p^1][idxD + 3 * Ns] = cadd(t1, cmuli_pos(t3));
        p ^= 1;
        __builtin_amdgcn_sched_barrier(0);
    }

    // stage 3 (Ns=64): idxD = j, write straight to global (coalesced runs)
    {
        float2 a0 = buf[w][p][j      ];
        float2 a1 = buf[w][p][j +  64];
        float2 a2 = buf[w][p][j + 128];
        float2 a3 = buf[w][p][j + 192];
        float sn, cs;
        __sincosf(-(float)(2.0 * M_PI) * (float)j / 256.0f, &sn, &cs);
        float2 w1 = make_float2(cs, sn);
        float2 w2 = cmul(w1, w1);
        float2 w3 = cmul(w2, w1);
        a1 = cmul(a1, w1); a2 = cmul(a2, w2); a3 = cmul(a3, w3);
        float2 t0=cadd(a0,a2), t1=csub(a0,a2), t2=cadd(a1,a3), t3=csub(a1,a3);
        float2* op = out + (size_t)L * NDIM;
        op[j      ] = cadd(t0, t2);
        op[j +  64] = cadd(t1, cmuli_neg(t3));
        op[j + 128] = csub(t0, t2);
        op[j + 192] = cadd(t1, cmuli_pos(t3));
    }
}

// ---------------------------------------------------------------------------
// Passes 2/3: in-place radix-4 DIF FFT along a strided axis.
// Tile 256 (FFT dim) x 16 (contiguous z), ld = 18 float2 (16B-aligned pairs).
// float4 global loads/stores. Output base-4 digit-reversed along the axis.
// y-pass: lineStride=256, outerStride=65536; x-pass: 65536 / 256.
// ---------------------------------------------------------------------------
__global__ __launch_bounds__(256) void fft_strided(float2* __restrict__ A,
                                                   int lineStride, int outerStride)
{
    __shared__ __align__(16) float2 tile[NDIM * 18];   // 36.9 KB
    __shared__ float2 tw[NDIM];          // 2 KB: tw[k] = exp(-2*pi*i*k/256)
    const int t = threadIdx.x;
    {
        float sn, cs;
        __sincosf(-(float)(2.0 * M_PI) * (float)t / 256.0f, &sn, &cs);
        tw[t] = make_float2(cs, sn);
    }
    const int l4 = t & 7, u8 = t >> 3;   // load layout: 8 float4 per tile row
    const int o = blockIdx.x >> 4, c = blockIdx.x & 15;
    const long long base = (long long)o * outerStride + c * 16;

    #pragma unroll
    for (int it = 0; it < 8; ++it) {
        int pos = u8 + it * 32;
        const float4 d = *(const float4*)&A[base + (long long)pos * lineStride + 2 * l4];
        tile[pos * 18 + 2 * l4    ] = make_float2(d.x, d.y);
        tile[pos * 18 + 2 * l4 + 1] = make_float2(d.z, d.w);
    }
    __syncthreads();

    const int l = t & 15, u = t >> 4;
    #pragma unroll
    for (int ls = 6; ls >= 0; ls -= 2) {           // s = 64, 16, 4, 1
        const int s = 1 << ls;
        #pragma unroll
        for (int it = 0; it < 4; ++it) {
            int m  = u + it * 16;                  // butterfly id in [0,64)
            int jm = m & (s - 1);
            int bidx = ((m >> ls) << (ls + 2)) + jm;
            float2 a  = tile[(bidx        ) * 18 + l];
            float2 b  = tile[(bidx +     s) * 18 + l];
            float2 cc = tile[(bidx + 2 * s) * 18 + l];
            float2 d  = tile[(bidx + 3 * s) * 18 + l];
            float2 t0=cadd(a,cc), t1=csub(a,cc), t2=cadd(b,d), t3=csub(b,d);
            float2 y0 = cadd(t0, t2);
            float2 y1 = cadd(t1, cmuli_neg(t3));
            float2 y2 = csub(t0, t2);
            float2 y3 = cadd(t1, cmuli_pos(t3));
            int k1 = jm << (6 - ls);               // 256/(4s) multiplier
            y1 = cmul(y1, tw[k1]);
            y2 = cmul(y2, tw[2 * k1]);
            y3 = cmul(y3, tw[3 * k1]);
            tile[(bidx        ) * 18 + l] = y0;
            tile[(bidx +     s) * 18 + l] = y1;
            tile[(bidx + 2 * s) * 18 + l] = y2;
            tile[(bidx + 3 * s) * 18 + l] = y3;
        }
        __syncthreads();
    }

    #pragma unroll
    for (int it = 0; it < 8; ++it) {
        int pos = u8 + it * 32;
        float2 e0 = tile[pos * 18 + 2 * l4], e1 = tile[pos * 18 + 2 * l4 + 1];
        *(float4*)&A[base + (long long)pos * lineStride + 2 * l4] =
            make_float4(e0.x, e0.y, e1.x, e1.y);
    }
}

// ---------------------------------------------------------------------------
// Pass 4: shell reduction, conjugate-pair scheme (each line read once,
// weight 2 for proper pairs). x,y axes are base-4 digit-reversed (dr4),
// z natural.
//
// v6: rounds 0/1/4/5 all fit one model: the 16 line-pair loads per thread
// execute as a SERIAL latency chain (round 5: VGPR=24 proves sched_barrier
// did not stop the sink; round 4's 8-serial staging halved residency,
// exactly 16->8). Enforcement now via DATA DEPENDENCE, not hints: load all
// 16 values as 64-bit, then asm volatile with "+v" ties on every value.
// The asm reads all 16 (loads must complete before it -> one waitcnt, all
// in flight) and writes all 16 (consumption can't be hoisted, loads can't
// sink). Addresses are SGPR-base + shared voffset, so peak VGPR ~48-64.
// ---------------------------------------------------------------------------
__global__ __launch_bounds__(256) void reduce_shells(const float2* __restrict__ A,
                                                     float* __restrict__ bins)
{
    __shared__ float bs[4][3 * NB];      // 6 KB, one histogram per wave
    const int t = threadIdx.x;
    const int w = t >> 6;
    for (int i = t; i < 4 * 3 * NB; i += 256) ((float*)bs)[i] = 0.f;
    __syncthreads();

    // ---- classify all jobs (entirely block-uniform -> SGPR math) ----
    int  Lk[8], Lpk[8], lc2[8];
    float wgt[8];
    #pragma unroll
    for (int jj = 0; jj < 8; ++jj) {
        int L = blockIdx.x * 8 + jj;         // storage-order line id
        int px = L >> 8, py = L & 255;
        int fx = dr4(px), fy = dr4(py);
        int fxp = (256 - fx) & 255, fyp = (256 - fy) & 255;
        int Lp = dr4(fxp) * 256 + dr4(fyp);  // partner line (storage order)
        int ax = (fx < 128) ? fx : 256 - fx;
        int ay = (fy < 128) ? fy : 256 - fy;
        int c2 = ax * ax + ay * ay;
        lc2[jj] = -1;
        if (Lp >= L && c2 < NB * NB) lc2[jj] = c2;
        // clamp inactive jobs to line 0: loads become L2-broadcast no-ops
        Lk[jj]  = (lc2[jj] < 0) ? 0 : L;
        Lpk[jj] = (lc2[jj] < 0) ? 0 : Lp;
        wgt[jj] = (Lp == L) ? 1.f : 2.f;
    }

    const int pz  = t;
    const int izc = (pz < 128) ? pz : 256 - pz;
    const int iz2 = izc * izc;
    const int pzp = (256 - pz) & 255;

    // ---- phase A: issue all 16 loads; asm tie forces them batched ----
    const double* Ad = (const double*)A;     // one float2 == one 64-bit load
    double z1d[8], z2d[8];
    #pragma unroll
    for (int jj = 0; jj < 8; ++jj) {
        z1d[jj] = Ad[(size_t)Lk[jj]  * 256 + pz];
        z2d[jj] = Ad[(size_t)Lpk[jj] * 256 + pzp];
    }
    asm volatile("" :
        "+v"(z1d[0]), "+v"(z1d[1]), "+v"(z1d[2]), "+v"(z1d[3]),
        "+v"(z1d[4]), "+v"(z1d[5]), "+v"(z1d[6]), "+v"(z1d[7]),
        "+v"(z2d[0]), "+v"(z2d[1]), "+v"(z2d[2]), "+v"(z2d[3]),
        "+v"(z2d[4]), "+v"(z2d[5]), "+v"(z2d[6]), "+v"(z2d[7]));

    // ---- phase B: unpack + accumulate (values already in registers) ----
    #pragma unroll
    for (int jj = 0; jj < 8; ++jj) {
        if (lc2[jj] < 0) continue;           // block-uniform branch
        int m = lc2[jj] + iz2;
        int lab = (int)sqrtf((float)m);
        if (lab >= NB) continue;             // dropped trash bin
        float2 a = __builtin_bit_cast(float2, z1d[jj]);
        float2 b = __builtin_bit_cast(float2, z2d[jj]);
        float F1r = 0.5f * (a.x + b.x);
        float F1i = 0.5f * (a.y - b.y);
        float F2r = 0.5f * (a.y + b.y);
        float F2i = 0.5f * (b.x - a.x);
        float g = wgt[jj];
        atomicAdd(&bs[w][lab],           g * (F1r * F2r + F1i * F2i));  // cross
        atomicAdd(&bs[w][NB + lab],      g * (F1r * F1r + F1i * F1i));  // p1
        atomicAdd(&bs[w][2 * NB + lab],  g * (F2r * F2r + F2i * F2i));  // p2
    }
    __syncthreads();

    for (int i = t; i < 3 * NB; i += 256) {
        float v = bs[0][i] + bs[1][i] + bs[2][i] + bs[3][i];
        if (v != 0.f) atomicAdd(&bins[i], v);
    }
}

// ---------------------------------------------------------------------------
__global__ void zero_bins(float* bins)
{
    int t = blockIdx.x * blockDim.x + threadIdx.x;
    if (t < 2 * 3 * NB) bins[t] = 0.f;
}

__global__ void finalize(const float* __restrict__ binsAll, float* __restrict__ out)
{
    __shared__ float red[256];
    const int t = threadIdx.x;
    const int b = t >> 7, bin = t & 127;
    const float* bb = binsAll + b * 3 * NB;
    float num = bb[bin], d1 = bb[NB + bin], d2 = bb[2 * NB + bin];
    float fsc = num / sqrtf(d1 * d2 + 1e-8f);
    red[t] = fsc * fsc;
    __syncthreads();
    for (int s = 128; s > 0; s >>= 1) {
        if (t < s) red[t] += red[t + s];
        __syncthreads();
    }
    if (t == 0) out[0] = 1.f - red[0] / 256.f;
}

__global__ void ws_too_small(float* out) { out[0] = -1.0e9f; }

// ---------------------------------------------------------------------------
extern "C" void kernel_launch(void* const* d_in, const int* in_sizes, int n_in,
                              void* d_out, int out_size, void* d_ws, size_t ws_size,
                              hipStream_t stream)
{
    const float* ref  = (const float*)d_in[0];
    const float* pred = (const float*)d_in[1];
    float* out = (float*)d_out;

    const size_t volBytes = (size_t)VOL * sizeof(float2);   // 134,217,728
    if (ws_size < volBytes + 4096) {
        ws_too_small<<<1, 1, 0, stream>>>(out);
        return;
    }
    float2* A   = (float2*)d_ws;
    float* bins = (float*)((char*)d_ws + volBytes);          // [2][3][128]

    zero_bins<<<1, 1024, 0, stream>>>(bins);

    for (int b = 0; b < 2; ++b) {
        fftz_pack  <<<16384, 256, 0, stream>>>(ref + (size_t)b * VOL,
                                               pred + (size_t)b * VOL, A);
        fft_strided<<<4096, 256, 0, stream>>>(A, 256,   65536);  // y-pass
        fft_strided<<<4096, 256, 0, stream>>>(A, 65536, 256);    // x-pass
        reduce_shells<<<8192, 256, 0, stream>>>(A, bins + b * 3 * NB);
    }
    finalize<<<1, 256, 0, stream>>>(bins, out);
}

// Round 7
// 671.169 us; speedup vs baseline: 1.0089x; 1.0089x over previous
//
#include <hip/hip_runtime.h>
#include <math.h>

#define NDIM 256
#define VOL  (NDIM*NDIM*NDIM)      // 16777216 elements per batch-channel volume
#define NB   128                    // kept bins 0..127; label 128 is dropped

// base-4 digit reversal of an 8-bit index (involution)
__device__ __forceinline__ int dr4(int x) {
    int b = (int)(__brev((unsigned)x) >> 24);
    return ((b >> 1) & 0x55) | ((b << 1) & 0xAA);
}
__device__ __forceinline__ float2 cmul(float2 a, float2 b) {
    return make_float2(a.x * b.x - a.y * b.y, a.x * b.y + a.y * b.x);
}
__device__ __forceinline__ float2 cadd(float2 a, float2 b){ return make_float2(a.x+b.x, a.y+b.y); }
__device__ __forceinline__ float2 csub(float2 a, float2 b){ return make_float2(a.x-b.x, a.y-b.y); }
__device__ __forceinline__ float2 cmuli_neg(float2 a){ return make_float2(a.y, -a.x); }  // -i*a
__device__ __forceinline__ float2 cmuli_pos(float2 a){ return make_float2(-a.y, a.x); }  // +i*a

// ---------------------------------------------------------------------------
// Pass 1: pack (ref + i*pred), radix-4 Stockham FFT along z. One WAVE per
// 256-pt line (wave-private LDS, no barriers). Stage 0 reads global directly;
// stage 3 writes global directly. Natural-order output.
// ---------------------------------------------------------------------------
__global__ __launch_bounds__(256) void fftz_pack(const float* __restrict__ re_in,
                                                 const float* __restrict__ im_in,
                                                 float2* __restrict__ out)
{
    __shared__ float2 buf[4][2][NDIM];   // 16 KB, per-wave double buffer
    const int t = threadIdx.x;
    const int w = t >> 6, j = t & 63;
    const int L = blockIdx.x * 4 + w;    // line id in [0, 65536)
    const float* rp = re_in + (size_t)L * NDIM;
    const float* ip = im_in + (size_t)L * NDIM;

    float2 v0 = make_float2(rp[j      ], ip[j      ]);
    float2 v1 = make_float2(rp[j +  64], ip[j +  64]);
    float2 v2 = make_float2(rp[j + 128], ip[j + 128]);
    float2 v3 = make_float2(rp[j + 192], ip[j + 192]);

    // stage 0 (Ns=1, twiddle = 1): write at 4j + r
    {
        float2 t0=cadd(v0,v2), t1=csub(v0,v2), t2=cadd(v1,v3), t3=csub(v1,v3);
        buf[w][0][4*j    ] = cadd(t0, t2);
        buf[w][0][4*j + 1] = cadd(t1, cmuli_neg(t3));
        buf[w][0][4*j + 2] = csub(t0, t2);
        buf[w][0][4*j + 3] = cadd(t1, cmuli_pos(t3));
    }
    __builtin_amdgcn_sched_barrier(0);

    int p = 0;
    #pragma unroll
    for (int stage = 1; stage <= 2; ++stage) {
        const int Ns = (stage == 1) ? 4 : 16;
        const int jm = j & (Ns - 1);
        float2 a0 = buf[w][p][j      ];
        float2 a1 = buf[w][p][j +  64];
        float2 a2 = buf[w][p][j + 128];
        float2 a3 = buf[w][p][j + 192];
        float sn, cs;
        __sincosf(-(float)(2.0 * M_PI) * (float)jm / (float)(4 * Ns), &sn, &cs);
        float2 w1 = make_float2(cs, sn);
        float2 w2 = cmul(w1, w1);
        float2 w3 = cmul(w2, w1);
        a1 = cmul(a1, w1); a2 = cmul(a2, w2); a3 = cmul(a3, w3);
        float2 t0=cadd(a0,a2), t1=csub(a0,a2), t2=cadd(a1,a3), t3=csub(a1,a3);
        const int idxD = (j / Ns) * (4 * Ns) + jm;
        buf[w][p^1][idxD         ] = cadd(t0, t2);
        buf[w][p^1][idxD +     Ns] = cadd(t1, cmuli_neg(t3));
        buf[w][p^1][idxD + 2 * Ns] = csub(t0, t2);
        buf[w][p^1][idxD + 3 * Ns] = cadd(t1, cmuli_pos(t3));
        p ^= 1;
        __builtin_amdgcn_sched_barrier(0);
    }

    // stage 3 (Ns=64): idxD = j, write straight to global (coalesced runs)
    {
        float2 a0 = buf[w][p][j      ];
        float2 a1 = buf[w][p][j +  64];
        float2 a2 = buf[w][p][j + 128];
        float2 a3 = buf[w][p][j + 192];
        float sn, cs;
        __sincosf(-(float)(2.0 * M_PI) * (float)j / 256.0f, &sn, &cs);
        float2 w1 = make_float2(cs, sn);
        float2 w2 = cmul(w1, w1);
        float2 w3 = cmul(w2, w1);
        a1 = cmul(a1, w1); a2 = cmul(a2, w2); a3 = cmul(a3, w3);
        float2 t0=cadd(a0,a2), t1=csub(a0,a2), t2=cadd(a1,a3), t3=csub(a1,a3);
        float2* op = out + (size_t)L * NDIM;
        op[j      ] = cadd(t0, t2);
        op[j +  64] = cadd(t1, cmuli_neg(t3));
        op[j + 128] = csub(t0, t2);
        op[j + 192] = cadd(t1, cmuli_pos(t3));
    }
}

// ---------------------------------------------------------------------------
// Passes 2/3: in-place radix-4 DIF FFT along a strided axis.
// Tile 256 (FFT dim) x 16 (contiguous z), ld = 18 float2 (16B-aligned pairs).
// float4 global loads/stores. Output base-4 digit-reversed along the axis.
// y-pass: lineStride=256, outerStride=65536; x-pass: 65536 / 256.
// ---------------------------------------------------------------------------
__global__ __launch_bounds__(256) void fft_strided(float2* __restrict__ A,
                                                   int lineStride, int outerStride)
{
    __shared__ __align__(16) float2 tile[NDIM * 18];   // 36.9 KB
    __shared__ float2 tw[NDIM];          // 2 KB: tw[k] = exp(-2*pi*i*k/256)
    const int t = threadIdx.x;
    {
        float sn, cs;
        __sincosf(-(float)(2.0 * M_PI) * (float)t / 256.0f, &sn, &cs);
        tw[t] = make_float2(cs, sn);
    }
    const int l4 = t & 7, u8 = t >> 3;   // load layout: 8 float4 per tile row
    const int o = blockIdx.x >> 4, c = blockIdx.x & 15;
    const long long base = (long long)o * outerStride + c * 16;

    #pragma unroll
    for (int it = 0; it < 8; ++it) {
        int pos = u8 + it * 32;
        const float4 d = *(const float4*)&A[base + (long long)pos * lineStride + 2 * l4];
        tile[pos * 18 + 2 * l4    ] = make_float2(d.x, d.y);
        tile[pos * 18 + 2 * l4 + 1] = make_float2(d.z, d.w);
    }
    __syncthreads();

    const int l = t & 15, u = t >> 4;
    #pragma unroll
    for (int ls = 6; ls >= 0; ls -= 2) {           // s = 64, 16, 4, 1
        const int s = 1 << ls;
        #pragma unroll
        for (int it = 0; it < 4; ++it) {
            int m  = u + it * 16;                  // butterfly id in [0,64)
            int jm = m & (s - 1);
            int bidx = ((m >> ls) << (ls + 2)) + jm;
            float2 a  = tile[(bidx        ) * 18 + l];
            float2 b  = tile[(bidx +     s) * 18 + l];
            float2 cc = tile[(bidx + 2 * s) * 18 + l];
            float2 d  = tile[(bidx + 3 * s) * 18 + l];
            float2 t0=cadd(a,cc), t1=csub(a,cc), t2=cadd(b,d), t3=csub(b,d);
            float2 y0 = cadd(t0, t2);
            float2 y1 = cadd(t1, cmuli_neg(t3));
            float2 y2 = csub(t0, t2);
            float2 y3 = cadd(t1, cmuli_pos(t3));
            int k1 = jm << (6 - ls);               // 256/(4s) multiplier
            y1 = cmul(y1, tw[k1]);
            y2 = cmul(y2, tw[2 * k1]);
            y3 = cmul(y3, tw[3 * k1]);
            tile[(bidx        ) * 18 + l] = y0;
            tile[(bidx +     s) * 18 + l] = y1;
            tile[(bidx + 2 * s) * 18 + l] = y2;
            tile[(bidx + 3 * s) * 18 + l] = y3;
        }
        __syncthreads();
    }

    #pragma unroll
    for (int it = 0; it < 8; ++it) {
        int pos = u8 + it * 32;
        float2 e0 = tile[pos * 18 + 2 * l4], e1 = tile[pos * 18 + 2 * l4 + 1];
        *(float4*)&A[base + (long long)pos * lineStride + 2 * l4] =
            make_float4(e0.x, e0.y, e1.x, e1.y);
    }
}

// ---------------------------------------------------------------------------
// Pass 4: shell reduction, conjugate-pair scheme (each line read once,
// weight 2 for proper pairs). x,y axes are base-4 digit-reversed (dr4),
// z natural.
//
// v7 = round-4 structure with the staging-loop GUARDS REMOVED. Evidence
// across rounds 1/4/5/6: per-job conditional guards around the loads put
// each load+store in its own basic block -> compiler serializes (r1: 16
// serial loads, 44k cy/wave; r4: 8 serial, 26k cy/wave — exact 2x). The
// guard-free unrolled (float4 load -> LDS store) x8 loop is byte-for-byte
// fft_strided's staging idiom, which sustains 3.4 TB/s. Inactive jobs
// clamp to line 0 (L2-broadcast); compute remains guarded.
// ---------------------------------------------------------------------------
__global__ __launch_bounds__(256) void reduce_shells(const float2* __restrict__ A,
                                                     float* __restrict__ bins)
{
    __shared__ __align__(16) float2 lines[8][2][NDIM]; // 32 KB: [0]=line L, [1]=line Lp
    __shared__ float bs[4][3 * NB];      // 6 KB, one histogram per wave
    const int t = threadIdx.x;
    const int w = t >> 6;
    for (int i = t; i < 4 * 3 * NB; i += 256) ((float*)bs)[i] = 0.f;

    // ---- classify all jobs (entirely block-uniform -> SGPR math) ----
    int  Lk[8], Lpk[8], lc2[8];
    float wgt[8];
    #pragma unroll
    for (int jj = 0; jj < 8; ++jj) {
        int L = blockIdx.x * 8 + jj;         // storage-order line id
        int px = L >> 8, py = L & 255;
        int fx = dr4(px), fy = dr4(py);
        int fxp = (256 - fx) & 255, fyp = (256 - fy) & 255;
        int Lp = dr4(fxp) * 256 + dr4(fyp);  // partner line (storage order)
        int ax = (fx < 128) ? fx : 256 - fx;
        int ay = (fy < 128) ? fy : 256 - fy;
        int c2 = ax * ax + ay * ay;
        lc2[jj] = -1;
        if (Lp >= L && c2 < NB * NB) lc2[jj] = c2;
        // clamp inactive jobs to line 0: loads become L2-broadcast no-ops
        Lk[jj]  = (lc2[jj] < 0) ? 0 : L;
        Lpk[jj] = (lc2[jj] < 0) ? 0 : Lp;
        wgt[jj] = (Lp == L) ? 1.f : 2.f;
    }

    // ---- stage all 8 line-pairs: UNGUARDED, fft_strided's exact idiom ----
    const int sel  = t >> 7;                 // 0: line L, 1: line Lp
    const int idx4 = t & 127;                // float4 index within the line
    #pragma unroll
    for (int jj = 0; jj < 8; ++jj) {
        int line = sel ? Lpk[jj] : Lk[jj];
        const float4 d = *(const float4*)&A[(size_t)line * 256 + 2 * idx4];
        *(float4*)&lines[jj][sel][2 * idx4] = d;
    }
    __syncthreads();                         // covers bs init + lines staging

    // ---- compute: everything from LDS ----
    const int pz  = t;
    const int izc = (pz < 128) ? pz : 256 - pz;
    const int iz2 = izc * izc;
    const int pzp = (256 - pz) & 255;

    #pragma unroll
    for (int jj = 0; jj < 8; ++jj) {
        if (lc2[jj] < 0) continue;           // block-uniform branch
        int m = lc2[jj] + iz2;
        int lab = (int)sqrtf((float)m);
        if (lab >= NB) continue;             // dropped trash bin
        float2 a = lines[jj][0][pz];
        float2 b = lines[jj][1][pzp];
        float F1r = 0.5f * (a.x + b.x);
        float F1i = 0.5f * (a.y - b.y);
        float F2r = 0.5f * (a.y + b.y);
        float F2i = 0.5f * (b.x - a.x);
        float g = wgt[jj];
        atomicAdd(&bs[w][lab],           g * (F1r * F2r + F1i * F2i));  // cross
        atomicAdd(&bs[w][NB + lab],      g * (F1r * F1r + F1i * F1i));  // p1
        atomicAdd(&bs[w][2 * NB + lab],  g * (F2r * F2r + F2i * F2i));  // p2
    }
    __syncthreads();

    for (int i = t; i < 3 * NB; i += 256) {
        float v = bs[0][i] + bs[1][i] + bs[2][i] + bs[3][i];
        if (v != 0.f) atomicAdd(&bins[i], v);
    }
}

// ---------------------------------------------------------------------------
__global__ void zero_bins(float* bins)
{
    int t = blockIdx.x * blockDim.x + threadIdx.x;
    if (t < 2 * 3 * NB) bins[t] = 0.f;
}

__global__ void finalize(const float* __restrict__ binsAll, float* __restrict__ out)
{
    __shared__ float red[256];
    const int t = threadIdx.x;
    const int b = t >> 7, bin = t & 127;
    const float* bb = binsAll + b * 3 * NB;
    float num = bb[bin], d1 = bb[NB + bin], d2 = bb[2 * NB + bin];
    float fsc = num / sqrtf(d1 * d2 + 1e-8f);
    red[t] = fsc * fsc;
    __syncthreads();
    for (int s = 128; s > 0; s >>= 1) {
        if (t < s) red[t] += red[t + s];
        __syncthreads();
    }
    if (t == 0) out[0] = 1.f - red[0] / 256.f;
}

__global__ void ws_too_small(float* out) { out[0] = -1.0e9f; }

// ---------------------------------------------------------------------------
extern "C" void kernel_launch(void* const* d_in, const int* in_sizes, int n_in,
                              void* d_out, int out_size, void* d_ws, size_t ws_size,
                              hipStream_t stream)
{
    const float* ref  = (const float*)d_in[0];
    const float* pred = (const float*)d_in[1];
    float* out = (float*)d_out;

    const size_t volBytes = (size_t)VOL * sizeof(float2);   // 134,217,728
    if (ws_size < volBytes + 4096) {
        ws_too_small<<<1, 1, 0, stream>>>(out);
        return;
    }
    float2* A   = (float2*)d_ws;
    float* bins = (float*)((char*)d_ws + volBytes);          // [2][3][128]

    zero_bins<<<1, 1024, 0, stream>>>(bins);

    for (int b = 0; b < 2; ++b) {
        fftz_pack  <<<16384, 256, 0, stream>>>(ref + (size_t)b * VOL,
                                               pred + (size_t)b * VOL, A);
        fft_strided<<<4096, 256, 0, stream>>>(A, 256,   65536);  // y-pass
        fft_strided<<<4096, 256, 0, stream>>>(A, 65536, 256);    // x-pass
        reduce_shells<<<8192, 256, 0, stream>>>(A, bins + b * 3 * NB);
    }
    finalize<<<1, 256, 0, stream>>>(bins, out);
}

// Round 8
// 653.745 us; speedup vs baseline: 1.0358x; 1.0267x over previous
//
#include <hip/hip_runtime.h>
#include <math.h>

#define NDIM 256
#define VOL  (NDIM*NDIM*NDIM)      // 16777216 elements per batch-channel volume
#define NB   128                    // kept bins 0..127; label 128 is dropped
#define LDIM 272                    // 256 + 16: one float2 pad per 16 elements
                                    // breaks the 64B-stride bank aliasing of
                                    // 8-element z-chunks (16l banks -> 2-way)

// base-4 digit reversal of an 8-bit index (involution)
__device__ __forceinline__ int dr4(int x) {
    int b = (int)(__brev((unsigned)x) >> 24);
    return ((b >> 1) & 0x55) | ((b << 1) & 0xAA);
}
__device__ __forceinline__ float2 cmul(float2 a, float2 b) {
    return make_float2(a.x * b.x - a.y * b.y, a.x * b.y + a.y * b.x);
}
__device__ __forceinline__ float2 cadd(float2 a, float2 b){ return make_float2(a.x+b.x, a.y+b.y); }
__device__ __forceinline__ float2 csub(float2 a, float2 b){ return make_float2(a.x-b.x, a.y-b.y); }
__device__ __forceinline__ float2 cmuli_neg(float2 a){ return make_float2(a.y, -a.x); }  // -i*a
__device__ __forceinline__ float2 cmuli_pos(float2 a){ return make_float2(-a.y, a.x); }  // +i*a

// ---------------------------------------------------------------------------
// Pass 1: pack (ref + i*pred), radix-4 Stockham FFT along z. One WAVE per
// 256-pt line (wave-private LDS, no barriers). Stage 0 reads global directly;
// stage 3 writes global directly. Natural-order output.
// ---------------------------------------------------------------------------
__global__ __launch_bounds__(256) void fftz_pack(const float* __restrict__ re_in,
                                                 const float* __restrict__ im_in,
                                                 float2* __restrict__ out)
{
    __shared__ float2 buf[4][2][NDIM];   // 16 KB, per-wave double buffer
    const int t = threadIdx.x;
    const int w = t >> 6, j = t & 63;
    const int L = blockIdx.x * 4 + w;    // line id in [0, 65536)
    const float* rp = re_in + (size_t)L * NDIM;
    const float* ip = im_in + (size_t)L * NDIM;

    float2 v0 = make_float2(rp[j      ], ip[j      ]);
    float2 v1 = make_float2(rp[j +  64], ip[j +  64]);
    float2 v2 = make_float2(rp[j + 128], ip[j + 128]);
    float2 v3 = make_float2(rp[j + 192], ip[j + 192]);

    // stage 0 (Ns=1, twiddle = 1): write at 4j + r
    {
        float2 t0=cadd(v0,v2), t1=csub(v0,v2), t2=cadd(v1,v3), t3=csub(v1,v3);
        buf[w][0][4*j    ] = cadd(t0, t2);
        buf[w][0][4*j + 1] = cadd(t1, cmuli_neg(t3));
        buf[w][0][4*j + 2] = csub(t0, t2);
        buf[w][0][4*j + 3] = cadd(t1, cmuli_pos(t3));
    }
    __builtin_amdgcn_sched_barrier(0);

    int p = 0;
    #pragma unroll
    for (int stage = 1; stage <= 2; ++stage) {
        const int Ns = (stage == 1) ? 4 : 16;
        const int jm = j & (Ns - 1);
        float2 a0 = buf[w][p][j      ];
        float2 a1 = buf[w][p][j +  64];
        float2 a2 = buf[w][p][j + 128];
        float2 a3 = buf[w][p][j + 192];
        float sn, cs;
        __sincosf(-(float)(2.0 * M_PI) * (float)jm / (float)(4 * Ns), &sn, &cs);
        float2 w1 = make_float2(cs, sn);
        float2 w2 = cmul(w1, w1);
        float2 w3 = cmul(w2, w1);
        a1 = cmul(a1, w1); a2 = cmul(a2, w2); a3 = cmul(a3, w3);
        float2 t0=cadd(a0,a2), t1=csub(a0,a2), t2=cadd(a1,a3), t3=csub(a1,a3);
        const int idxD = (j / Ns) * (4 * Ns) + jm;
        buf[w][p^1][idxD         ] = cadd(t0, t2);
        buf[w][p^1][idxD +     Ns] = cadd(t1, cmuli_neg(t3));
        buf[w][p^1][idxD + 2 * Ns] = csub(t0, t2);
        buf[w][p^1][idxD + 3 * Ns] = cadd(t1, cmuli_pos(t3));
        p ^= 1;
        __builtin_amdgcn_sched_barrier(0);
    }

    // stage 3 (Ns=64): idxD = j, write straight to global (coalesced runs)
    {
        float2 a0 = buf[w][p][j      ];
        float2 a1 = buf[w][p][j +  64];
        float2 a2 = buf[w][p][j + 128];
        float2 a3 = buf[w][p][j + 192];
        float sn, cs;
        __sincosf(-(float)(2.0 * M_PI) * (float)j / 256.0f, &sn, &cs);
        float2 w1 = make_float2(cs, sn);
        float2 w2 = cmul(w1, w1);
        float2 w3 = cmul(w2, w1);
        a1 = cmul(a1, w1); a2 = cmul(a2, w2); a3 = cmul(a3, w3);
        float2 t0=cadd(a0,a2), t1=csub(a0,a2), t2=cadd(a1,a3), t3=csub(a1,a3);
        float2* op = out + (size_t)L * NDIM;
        op[j      ] = cadd(t0, t2);
        op[j +  64] = cadd(t1, cmuli_neg(t3));
        op[j + 128] = csub(t0, t2);
        op[j + 192] = cadd(t1, cmuli_pos(t3));
    }
}

// ---------------------------------------------------------------------------
// Passes 2/3: in-place radix-4 DIF FFT along a strided axis.
// Tile 256 (FFT dim) x 16 (contiguous z), ld = 18 float2 (16B-aligned pairs).
// float4 global loads/stores. Output base-4 digit-reversed along the axis.
// y-pass: lineStride=256, outerStride=65536; x-pass: 65536 / 256.
// ---------------------------------------------------------------------------
__global__ __launch_bounds__(256) void fft_strided(float2* __restrict__ A,
                                                   int lineStride, int outerStride)
{
    __shared__ __align__(16) float2 tile[NDIM * 18];   // 36.9 KB
    __shared__ float2 tw[NDIM];          // 2 KB: tw[k] = exp(-2*pi*i*k/256)
    const int t = threadIdx.x;
    {
        float sn, cs;
        __sincosf(-(float)(2.0 * M_PI) * (float)t / 256.0f, &sn, &cs);
        tw[t] = make_float2(cs, sn);
    }
    const int l4 = t & 7, u8 = t >> 3;   // load layout: 8 float4 per tile row
    const int o = blockIdx.x >> 4, c = blockIdx.x & 15;
    const long long base = (long long)o * outerStride + c * 16;

    #pragma unroll
    for (int it = 0; it < 8; ++it) {
        int pos = u8 + it * 32;
        const float4 d = *(const float4*)&A[base + (long long)pos * lineStride + 2 * l4];
        tile[pos * 18 + 2 * l4    ] = make_float2(d.x, d.y);
        tile[pos * 18 + 2 * l4 + 1] = make_float2(d.z, d.w);
    }
    __syncthreads();

    const int l = t & 15, u = t >> 4;
    #pragma unroll
    for (int ls = 6; ls >= 0; ls -= 2) {           // s = 64, 16, 4, 1
        const int s = 1 << ls;
        #pragma unroll
        for (int it = 0; it < 4; ++it) {
            int m  = u + it * 16;                  // butterfly id in [0,64)
            int jm = m & (s - 1);
            int bidx = ((m >> ls) << (ls + 2)) + jm;
            float2 a  = tile[(bidx        ) * 18 + l];
            float2 b  = tile[(bidx +     s) * 18 + l];
            float2 cc = tile[(bidx + 2 * s) * 18 + l];
            float2 d  = tile[(bidx + 3 * s) * 18 + l];
            float2 t0=cadd(a,cc), t1=csub(a,cc), t2=cadd(b,d), t3=csub(b,d);
            float2 y0 = cadd(t0, t2);
            float2 y1 = cadd(t1, cmuli_neg(t3));
            float2 y2 = csub(t0, t2);
            float2 y3 = cadd(t1, cmuli_pos(t3));
            int k1 = jm << (6 - ls);               // 256/(4s) multiplier
            y1 = cmul(y1, tw[k1]);
            y2 = cmul(y2, tw[2 * k1]);
            y3 = cmul(y3, tw[3 * k1]);
            tile[(bidx        ) * 18 + l] = y0;
            tile[(bidx +     s) * 18 + l] = y1;
            tile[(bidx + 2 * s) * 18 + l] = y2;
            tile[(bidx + 3 * s) * 18 + l] = y3;
        }
        __syncthreads();
    }

    #pragma unroll
    for (int it = 0; it < 8; ++it) {
        int pos = u8 + it * 32;
        float2 e0 = tile[pos * 18 + 2 * l4], e1 = tile[pos * 18 + 2 * l4 + 1];
        *(float4*)&A[base + (long long)pos * lineStride + 2 * l4] =
            make_float4(e0.x, e0.y, e1.x, e1.y);
    }
}

// ---------------------------------------------------------------------------
// Pass 4: shell reduction, conjugate-pair scheme.
//
// v8: rounds 1-7 showed dur ~104-120 us INVARIANT to occupancy (71% r1,
// 36% r4, 38% r7) and load structure -> shared per-CU throughput bound,
// not latency. The invariant across all variants: per-lane LDS histogram
// atomics where ADJACENT LANES COMPUTE THE SAME SHELL LABEL (lab changes
// by izc/lab per z step -> 10-30 lanes share an address -> DS same-address
// serialization, ~1-2k cy/wave of exclusive LDS-pipe time; not visible in
// VALUBusy or SQ_LDS_BANK_CONFLICT).
// Fix: thread (jj=t>>5, l=t&31) owns 8 CONSECUTIVE z of ONE line-pair;
// labels are monotone along the chunk -> register run-accumulation, flush
// on label change (~2-3 flushes vs 24 per-lane atomics; flushes from
// different lanes hit DIFFERENT labels -> bank-parallel). Line layout
// padded (z + (z>>4)) so the 64B-stride chunk reads are <=2-way conflicts.
// Classification recomputed per-thread scalarly (runtime-indexed arrays
// would spill to scratch). Staging = r7's proven unguarded idiom.
// ---------------------------------------------------------------------------
__global__ __launch_bounds__(256) void reduce_shells(const float2* __restrict__ A,
                                                     float* __restrict__ bins)
{
    __shared__ __align__(16) float2 lines[8][2][LDIM]; // 34 KB, padded layout
    __shared__ float bs[2][3 * NB];      // 3 KB, one histogram per half-block
    const int t = threadIdx.x;
    for (int i = t; i < 2 * 3 * NB; i += 256) ((float*)bs)[i] = 0.f;

    // ---- classify all jobs for staging (block-uniform, static indexing) ----
    int Lk[8], Lpk[8];
    #pragma unroll
    for (int jj = 0; jj < 8; ++jj) {
        int L = blockIdx.x * 8 + jj;         // storage-order line id
        int px = L >> 8, py = L & 255;
        int fx = dr4(px), fy = dr4(py);
        int fxp = (256 - fx) & 255, fyp = (256 - fy) & 255;
        int Lp = dr4(fxp) * 256 + dr4(fyp);  // partner line (storage order)
        int ax = (fx < 128) ? fx : 256 - fx;
        int ay = (fy < 128) ? fy : 256 - fy;
        int c2 = ax * ax + ay * ay;
        bool act = (Lp >= L) && (c2 < NB * NB);
        Lk[jj]  = act ? L  : 0;              // inactive -> L2-broadcast line 0
        Lpk[jj] = act ? Lp : 0;
    }

    // ---- stage all 8 line-pairs: unguarded float4 -> padded LDS ----
    const int sel  = t >> 7;                 // 0: line L, 1: line Lp
    const int idx4 = t & 127;                // float4 index within the line
    #pragma unroll
    for (int jj = 0; jj < 8; ++jj) {
        int line = sel ? Lpk[jj] : Lk[jj];
        const float4 d = *(const float4*)&A[(size_t)line * 256 + 2 * idx4];
        int z = 2 * idx4;                    // pad keeps float2-pairs adjacent
        *(float4*)&lines[jj][sel][z + (z >> 4)] = d;
    }
    __syncthreads();                         // covers bs init + staging

    // ---- compute: this thread's job, scalar classification (no arrays) ----
    const int jj = t >> 5;                   // job id       (uniform per 32 t)
    const int l  = t & 31;                   // z-chunk id: pz in [8l, 8l+8)
    {
        int L = blockIdx.x * 8 + jj;
        int px = L >> 8, py = L & 255;
        int fx = dr4(px), fy = dr4(py);
        int fxp = (256 - fx) & 255, fyp = (256 - fy) & 255;
        int Lp = dr4(fxp) * 256 + dr4(fyp);
        int ax = (fx < 128) ? fx : 256 - fx;
        int ay = (fy < 128) ? fy : 256 - fy;
        int c2 = ax * ax + ay * ay;
        if (Lp >= L && c2 < NB * NB) {
            const float g = (Lp == L) ? 1.f : 2.f;
            const int w2 = t >> 7;
            int curLab = -1;
            float a0 = 0.f, a1 = 0.f, a2 = 0.f;
            #pragma unroll
            for (int k = 0; k < 8; ++k) {
                const int pz  = l * 8 + k;
                const int izc = (pz < 128) ? pz : 256 - pz;
                const int lab = (int)sqrtf((float)(c2 + izc * izc));
                const int zp  = (256 - pz) & 255;
                float2 a = lines[jj][0][pz + (pz >> 4)];
                float2 b = lines[jj][1][zp + (zp >> 4)];
                float F1r = 0.5f * (a.x + b.x);
                float F1i = 0.5f * (a.y - b.y);
                float F2r = 0.5f * (a.y + b.y);
                float F2i = 0.5f * (b.x - a.x);
                float v0 = g * (F1r * F2r + F1i * F2i);
                float v1 = g * (F1r * F1r + F1i * F1i);
                float v2 = g * (F2r * F2r + F2i * F2i);
                if (lab != curLab) {
                    if (curLab >= 0 && curLab < NB) {
                        atomicAdd(&bs[w2][curLab],          a0);
                        atomicAdd(&bs[w2][NB + curLab],     a1);
                        atomicAdd(&bs[w2][2 * NB + curLab], a2);
                    }
                    curLab = lab; a0 = v0; a1 = v1; a2 = v2;
                } else {
                    a0 += v0; a1 += v1; a2 += v2;
                }
            }
            if (curLab >= 0 && curLab < NB) {
                atomicAdd(&bs[w2][curLab],          a0);
                atomicAdd(&bs[w2][NB + curLab],     a1);
                atomicAdd(&bs[w2][2 * NB + curLab], a2);
            }
        }
    }
    __syncthreads();

    for (int i = t; i < 3 * NB; i += 256) {
        float v = bs[0][i] + bs[1][i];
        if (v != 0.f) atomicAdd(&bins[i], v);
    }
}

// ---------------------------------------------------------------------------
__global__ void zero_bins(float* bins)
{
    int t = blockIdx.x * blockDim.x + threadIdx.x;
    if (t < 2 * 3 * NB) bins[t] = 0.f;
}

__global__ void finalize(const float* __restrict__ binsAll, float* __restrict__ out)
{
    __shared__ float red[256];
    const int t = threadIdx.x;
    const int b = t >> 7, bin = t & 127;
    const float* bb = binsAll + b * 3 * NB;
    float num = bb[bin], d1 = bb[NB + bin], d2 = bb[2 * NB + bin];
    float fsc = num / sqrtf(d1 * d2 + 1e-8f);
    red[t] = fsc * fsc;
    __syncthreads();
    for (int s = 128; s > 0; s >>= 1) {
        if (t < s) red[t] += red[t + s];
        __syncthreads();
    }
    if (t == 0) out[0] = 1.f - red[0] / 256.f;
}

__global__ void ws_too_small(float* out) { out[0] = -1.0e9f; }

// ---------------------------------------------------------------------------
extern "C" void kernel_launch(void* const* d_in, const int* in_sizes, int n_in,
                              void* d_out, int out_size, void* d_ws, size_t ws_size,
                              hipStream_t stream)
{
    const float* ref  = (const float*)d_in[0];
    const float* pred = (const float*)d_in[1];
    float* out = (float*)d_out;

    const size_t volBytes = (size_t)VOL * sizeof(float2);   // 134,217,728
    if (ws_size < volBytes + 4096) {
        ws_too_small<<<1, 1, 0, stream>>>(out);
        return;
    }
    float2* A   = (float2*)d_ws;
    float* bins = (float*)((char*)d_ws + volBytes);          // [2][3][128]

    zero_bins<<<1, 1024, 0, stream>>>(bins);

    for (int b = 0; b < 2; ++b) {
        fftz_pack  <<<16384, 256, 0, stream>>>(ref + (size_t)b * VOL,
                                               pred + (size_t)b * VOL, A);
        fft_strided<<<4096, 256, 0, stream>>>(A, 256,   65536);  // y-pass
        fft_strided<<<4096, 256, 0, stream>>>(A, 65536, 256);    // x-pass
        reduce_shells<<<8192, 256, 0, stream>>>(A, bins + b * 3 * NB);
    }
    finalize<<<1, 256, 0, stream>>>(bins, out);
}

// Round 9
// 649.147 us; speedup vs baseline: 1.0431x; 1.0071x over previous
//
#include <hip/hip_runtime.h>
#include <math.h>

#define NDIM 256
#define VOL  (NDIM*NDIM*NDIM)      // 16777216 elements per batch-channel volume
#define NB   128                    // kept bins 0..127; label 128 is dropped
#define LDIM 272                    // 256 + 16: one float2 pad per 16 elements
#define NJOBS 32770                 // canonical conjugate pairs: 127*256 + 2*129
#define JPB   16                    // jobs per block
#define RS_GRID ((NJOBS + JPB - 1) / JPB)   // 2049

// base-4 digit reversal of an 8-bit index (involution)
__device__ __forceinline__ int dr4(int x) {
    int b = (int)(__brev((unsigned)x) >> 24);
    return ((b >> 1) & 0x55) | ((b << 1) & 0xAA);
}
__device__ __forceinline__ float2 cmul(float2 a, float2 b) {
    return make_float2(a.x * b.x - a.y * b.y, a.x * b.y + a.y * b.x);
}
__device__ __forceinline__ float2 cadd(float2 a, float2 b){ return make_float2(a.x+b.x, a.y+b.y); }
__device__ __forceinline__ float2 csub(float2 a, float2 b){ return make_float2(a.x-b.x, a.y-b.y); }
__device__ __forceinline__ float2 cmuli_neg(float2 a){ return make_float2(a.y, -a.x); }  // -i*a
__device__ __forceinline__ float2 cmuli_pos(float2 a){ return make_float2(-a.y, a.x); }  // +i*a

// job id -> canonical frequency pair (fx, fy).
// j < 32512: fy = 1 + (j>>8) in [1,127], fx = j&255.
// else: boundary rows fy in {0,128}, fx in [0,128].
__device__ __forceinline__ void job_to_freq(int j, int* fx, int* fy) {
    if (j < 32512) { *fy = 1 + (j >> 8); *fx = j & 255; }
    else {
        int jb = j - 32512;                  // [0, 258)
        *fy = (jb < 129) ? 0 : 128;
        *fx = (jb < 129) ? jb : jb - 129;    // [0,128]
    }
}

// ---------------------------------------------------------------------------
// Pass 1: pack (ref + i*pred), radix-4 Stockham FFT along z. One WAVE per
// 256-pt line (wave-private LDS, no barriers). Stage 0 reads global directly;
// stage 3 writes global directly. Natural-order output.
// ---------------------------------------------------------------------------
__global__ __launch_bounds__(256) void fftz_pack(const float* __restrict__ re_in,
                                                 const float* __restrict__ im_in,
                                                 float2* __restrict__ out)
{
    __shared__ float2 buf[4][2][NDIM];   // 16 KB, per-wave double buffer
    const int t = threadIdx.x;
    const int w = t >> 6, j = t & 63;
    const int L = blockIdx.x * 4 + w;    // line id in [0, 65536)
    const float* rp = re_in + (size_t)L * NDIM;
    const float* ip = im_in + (size_t)L * NDIM;

    float2 v0 = make_float2(rp[j      ], ip[j      ]);
    float2 v1 = make_float2(rp[j +  64], ip[j +  64]);
    float2 v2 = make_float2(rp[j + 128], ip[j + 128]);
    float2 v3 = make_float2(rp[j + 192], ip[j + 192]);

    // stage 0 (Ns=1, twiddle = 1): write at 4j + r
    {
        float2 t0=cadd(v0,v2), t1=csub(v0,v2), t2=cadd(v1,v3), t3=csub(v1,v3);
        buf[w][0][4*j    ] = cadd(t0, t2);
        buf[w][0][4*j + 1] = cadd(t1, cmuli_neg(t3));
        buf[w][0][4*j + 2] = csub(t0, t2);
        buf[w][0][4*j + 3] = cadd(t1, cmuli_pos(t3));
    }
    __builtin_amdgcn_sched_barrier(0);

    int p = 0;
    #pragma unroll
    for (int stage = 1; stage <= 2; ++stage) {
        const int Ns = (stage == 1) ? 4 : 16;
        const int jm = j & (Ns - 1);
        float2 a0 = buf[w][p][j      ];
        float2 a1 = buf[w][p][j +  64];
        float2 a2 = buf[w][p][j + 128];
        float2 a3 = buf[w][p][j + 192];
        float sn, cs;
        __sincosf(-(float)(2.0 * M_PI) * (float)jm / (float)(4 * Ns), &sn, &cs);
        float2 w1 = make_float2(cs, sn);
        float2 w2 = cmul(w1, w1);
        float2 w3 = cmul(w2, w1);
        a1 = cmul(a1, w1); a2 = cmul(a2, w2); a3 = cmul(a3, w3);
        float2 t0=cadd(a0,a2), t1=csub(a0,a2), t2=cadd(a1,a3), t3=csub(a1,a3);
        const int idxD = (j / Ns) * (4 * Ns) + jm;
        buf[w][p^1][idxD         ] = cadd(t0, t2);
        buf[w][p^1][idxD +     Ns] = cadd(t1, cmuli_neg(t3));
        buf[w][p^1][idxD + 2 * Ns] = csub(t0, t2);
        buf[w][p^1][idxD + 3 * Ns] = cadd(t1, cmuli_pos(t3));
        p ^= 1;
        __builtin_amdgcn_sched_barrier(0);
    }

    // stage 3 (Ns=64): idxD = j, write straight to global (coalesced runs)
    {
        float2 a0 = buf[w][p][j      ];
        float2 a1 = buf[w][p][j +  64];
        float2 a2 = buf[w][p][j + 128];
        float2 a3 = buf[w][p][j + 192];
        float sn, cs;
        __sincosf(-(float)(2.0 * M_PI) * (float)j / 256.0f, &sn, &cs);
        float2 w1 = make_float2(cs, sn);
        float2 w2 = cmul(w1, w1);
        float2 w3 = cmul(w2, w1);
        a1 = cmul(a1, w1); a2 = cmul(a2, w2); a3 = cmul(a3, w3);
        float2 t0=cadd(a0,a2), t1=csub(a0,a2), t2=cadd(a1,a3), t3=csub(a1,a3);
        float2* op = out + (size_t)L * NDIM;
        op[j      ] = cadd(t0, t2);
        op[j +  64] = cadd(t1, cmuli_neg(t3));
        op[j + 128] = csub(t0, t2);
        op[j + 192] = cadd(t1, cmuli_pos(t3));
    }
}

// ---------------------------------------------------------------------------
// Passes 2/3: in-place radix-4 DIF FFT along a strided axis.
// Tile 256 (FFT dim) x 16 (contiguous z), ld = 18 float2 (16B-aligned pairs).
// float4 global loads/stores. Output base-4 digit-reversed along the axis.
// y-pass: lineStride=256, outerStride=65536; x-pass: 65536 / 256.
// ---------------------------------------------------------------------------
__global__ __launch_bounds__(256) void fft_strided(float2* __restrict__ A,
                                                   int lineStride, int outerStride)
{
    __shared__ __align__(16) float2 tile[NDIM * 18];   // 36.9 KB
    __shared__ float2 tw[NDIM];          // 2 KB: tw[k] = exp(-2*pi*i*k/256)
    const int t = threadIdx.x;
    {
        float sn, cs;
        __sincosf(-(float)(2.0 * M_PI) * (float)t / 256.0f, &sn, &cs);
        tw[t] = make_float2(cs, sn);
    }
    const int l4 = t & 7, u8 = t >> 3;   // load layout: 8 float4 per tile row
    const int o = blockIdx.x >> 4, c = blockIdx.x & 15;
    const long long base = (long long)o * outerStride + c * 16;

    #pragma unroll
    for (int it = 0; it < 8; ++it) {
        int pos = u8 + it * 32;
        const float4 d = *(const float4*)&A[base + (long long)pos * lineStride + 2 * l4];
        tile[pos * 18 + 2 * l4    ] = make_float2(d.x, d.y);
        tile[pos * 18 + 2 * l4 + 1] = make_float2(d.z, d.w);
    }
    __syncthreads();

    const int l = t & 15, u = t >> 4;
    #pragma unroll
    for (int ls = 6; ls >= 0; ls -= 2) {           // s = 64, 16, 4, 1
        const int s = 1 << ls;
        #pragma unroll
        for (int it = 0; it < 4; ++it) {
            int m  = u + it * 16;                  // butterfly id in [0,64)
            int jm = m & (s - 1);
            int bidx = ((m >> ls) << (ls + 2)) + jm;
            float2 a  = tile[(bidx        ) * 18 + l];
            float2 b  = tile[(bidx +     s) * 18 + l];
            float2 cc = tile[(bidx + 2 * s) * 18 + l];
            float2 d  = tile[(bidx + 3 * s) * 18 + l];
            float2 t0=cadd(a,cc), t1=csub(a,cc), t2=cadd(b,d), t3=csub(b,d);
            float2 y0 = cadd(t0, t2);
            float2 y1 = cadd(t1, cmuli_neg(t3));
            float2 y2 = csub(t0, t2);
            float2 y3 = cadd(t1, cmuli_pos(t3));
            int k1 = jm << (6 - ls);               // 256/(4s) multiplier
            y1 = cmul(y1, tw[k1]);
            y2 = cmul(y2, tw[2 * k1]);
            y3 = cmul(y3, tw[3 * k1]);
            tile[(bidx        ) * 18 + l] = y0;
            tile[(bidx +     s) * 18 + l] = y1;
            tile[(bidx + 2 * s) * 18 + l] = y2;
            tile[(bidx + 3 * s) * 18 + l] = y3;
        }
        __syncthreads();
    }

    #pragma unroll
    for (int it = 0; it < 8; ++it) {
        int pos = u8 + it * 32;
        float2 e0 = tile[pos * 18 + 2 * l4], e1 = tile[pos * 18 + 2 * l4 + 1];
        *(float4*)&A[base + (long long)pos * lineStride + 2 * l4] =
            make_float4(e0.x, e0.y, e1.x, e1.y);
    }
}

// ---------------------------------------------------------------------------
// Pass 4: shell reduction.
//
// v9 DENSITY: 8 rounds showed ~100us invariant to load/atomic/occupancy
// structure, while fft_strided (worse coalescing!) moves bytes 3.4x faster.
// The real differentiator is USEFUL bytes resident per CU: fft 4x32KB=128KB,
// reduce_shells only ~40KB (half of its jobs dead: Lp<L skip + out-of-sphere
// -> ~40% active). Fix both factors:
//  (1) enumerate jobs directly as canonical conjugate pairs in FREQUENCY
//      space (closed form, 32770 jobs, ~79% in-sphere) -- no pair-skip waste;
//  (2) 16 jobs/block, 64KB padded line buffer, 2 blocks/CU -> 128KB useful
//      resident per CU, matching fft_strided's proven regime.
// Staging: r7's unguarded clamp idiom. Compute: r8's run-accumulated flush
// (16 z per thread -> fewer flushes/z). Padded layout keeps stride-16
// compute reads conflict-free.
// ---------------------------------------------------------------------------
__global__ __launch_bounds__(256) void reduce_shells(const float2* __restrict__ A,
                                                     float* __restrict__ bins)
{
    __shared__ __align__(16) float2 lines[JPB][2][LDIM]; // 68 KB padded
    __shared__ float bs[2][3 * NB];      // 3 KB, one histogram per half-block
    const int t = threadIdx.x;
    for (int i = t; i < 2 * 3 * NB; i += 256) ((float*)bs)[i] = 0.f;

    // ---- classify all jobs for staging (block-uniform, static indexing) ----
    int Lk[JPB], Lpk[JPB];
    #pragma unroll
    for (int jj = 0; jj < JPB; ++jj) {
        int j = blockIdx.x * JPB + jj;
        int fx, fy; job_to_freq(j < NJOBS ? j : 0, &fx, &fy);
        int ax = (fx <= 128) ? fx : 256 - fx;
        int ay = (fy <= 128) ? fy : 256 - fy;
        bool act = (j < NJOBS) && (ax * ax + ay * ay < NB * NB);
        int fxp = (256 - fx) & 255, fyp = (256 - fy) & 255;
        Lk[jj]  = act ? (dr4(fx)  * 256 + dr4(fy))  : 0;
        Lpk[jj] = act ? (dr4(fxp) * 256 + dr4(fyp)) : 0;
    }

    // ---- stage all line-pairs: unguarded float4 -> padded LDS ----
    const int sel  = t >> 7;                 // 0: line L, 1: line Lp
    const int idx4 = t & 127;                // float4 index within the line
    #pragma unroll
    for (int jj = 0; jj < JPB; ++jj) {
        int line = sel ? Lpk[jj] : Lk[jj];
        const float4 d = *(const float4*)&A[(size_t)line * 256 + 2 * idx4];
        int z = 2 * idx4;                    // pad keeps float2-pairs adjacent
        *(float4*)&lines[jj][sel][z + (z >> 4)] = d;
    }
    __syncthreads();                         // covers bs init + staging

    // ---- compute: thread (jj = t>>4, l = t&15) owns z in [16l, 16l+16) ----
    {
        const int jj = t >> 4;
        const int l  = t & 15;
        int j = blockIdx.x * JPB + jj;
        int fx, fy; job_to_freq(j < NJOBS ? j : 0, &fx, &fy);
        int ax = (fx <= 128) ? fx : 256 - fx;
        int ay = (fy <= 128) ? fy : 256 - fy;
        int c2 = ax * ax + ay * ay;
        if (j < NJOBS && c2 < NB * NB) {
            // self-pair (fx,fy both in {0,128}) -> weight 1, else 2
            const bool self = ((fx & 127) == 0) && ((fy & 127) == 0);
            const float g = self ? 1.f : 2.f;
            const int w2 = t >> 7;
            int curLab = -1;
            float a0 = 0.f, a1 = 0.f, a2 = 0.f;
            #pragma unroll
            for (int k = 0; k < 16; ++k) {
                const int pz  = l * 16 + k;
                const int izc = (pz < 128) ? pz : 256 - pz;
                const int lab = (int)sqrtf((float)(c2 + izc * izc));
                const int zp  = (256 - pz) & 255;
                float2 a = lines[jj][0][pz + (pz >> 4)];
                float2 b = lines[jj][1][zp + (zp >> 4)];
                float F1r = 0.5f * (a.x + b.x);
                float F1i = 0.5f * (a.y - b.y);
                float F2r = 0.5f * (a.y + b.y);
                float F2i = 0.5f * (b.x - a.x);
                float v0 = g * (F1r * F2r + F1i * F2i);
                float v1 = g * (F1r * F1r + F1i * F1i);
                float v2 = g * (F2r * F2r + F2i * F2i);
                if (lab != curLab) {
                    if (curLab >= 0 && curLab < NB) {
                        atomicAdd(&bs[w2][curLab],          a0);
                        atomicAdd(&bs[w2][NB + curLab],     a1);
                        atomicAdd(&bs[w2][2 * NB + curLab], a2);
                    }
                    curLab = lab; a0 = v0; a1 = v1; a2 = v2;
                } else {
                    a0 += v0; a1 += v1; a2 += v2;
                }
            }
            if (curLab >= 0 && curLab < NB) {
                atomicAdd(&bs[w2][curLab],          a0);
                atomicAdd(&bs[w2][NB + curLab],     a1);
                atomicAdd(&bs[w2][2 * NB + curLab], a2);
            }
        }
    }
    __syncthreads();

    for (int i = t; i < 3 * NB; i += 256) {
        float v = bs[0][i] + bs[1][i];
        if (v != 0.f) atomicAdd(&bins[i], v);
    }
}

// ---------------------------------------------------------------------------
__global__ void zero_bins(float* bins)
{
    int t = blockIdx.x * blockDim.x + threadIdx.x;
    if (t < 2 * 3 * NB) bins[t] = 0.f;
}

__global__ void finalize(const float* __restrict__ binsAll, float* __restrict__ out)
{
    __shared__ float red[256];
    const int t = threadIdx.x;
    const int b = t >> 7, bin = t & 127;
    const float* bb = binsAll + b * 3 * NB;
    float num = bb[bin], d1 = bb[NB + bin], d2 = bb[2 * NB + bin];
    float fsc = num / sqrtf(d1 * d2 + 1e-8f);
    red[t] = fsc * fsc;
    __syncthreads();
    for (int s = 128; s > 0; s >>= 1) {
        if (t < s) red[t] += red[t + s];
        __syncthreads();
    }
    if (t == 0) out[0] = 1.f - red[0] / 256.f;
}

__global__ void ws_too_small(float* out) { out[0] = -1.0e9f; }

// ---------------------------------------------------------------------------
extern "C" void kernel_launch(void* const* d_in, const int* in_sizes, int n_in,
                              void* d_out, int out_size, void* d_ws, size_t ws_size,
                              hipStream_t stream)
{
    const float* ref  = (const float*)d_in[0];
    const float* pred = (const float*)d_in[1];
    float* out = (float*)d_out;

    const size_t volBytes = (size_t)VOL * sizeof(float2);   // 134,217,728
    if (ws_size < volBytes + 4096) {
        ws_too_small<<<1, 1, 0, stream>>>(out);
        return;
    }
    float2* A   = (float2*)d_ws;
    float* bins = (float*)((char*)d_ws + volBytes);          // [2][3][128]

    zero_bins<<<1, 1024, 0, stream>>>(bins);

    for (int b = 0; b < 2; ++b) {
        fftz_pack  <<<16384, 256, 0, stream>>>(ref + (size_t)b * VOL,
                                               pred + (size_t)b * VOL, A);
        fft_strided<<<4096, 256, 0, stream>>>(A, 256,   65536);  // y-pass
        fft_strided<<<4096, 256, 0, stream>>>(A, 65536, 256);    // x-pass
        reduce_shells<<<RS_GRID, 256, 0, stream>>>(A, bins + b * 3 * NB);
    }
    finalize<<<1, 256, 0, stream>>>(bins, out);
}